// Round 1
// baseline (213.338 us; speedup 1.0000x reference)
//
#include <hip/hip_runtime.h>
#include <hip/hip_bf16.h>

#define FDIM 1024
#define BROWS 16384
#define DELTA_C 0.3f
#define LAMB_C 0.0005f

typedef __bf16 bf8v __attribute__((ext_vector_type(8)));
typedef float f4v __attribute__((ext_vector_type(4)));

__device__ __forceinline__ unsigned short f2bf(float f) {
  unsigned u = __builtin_bit_cast(unsigned, f);
  u += 0x7fffu + ((u >> 16) & 1u);
  return (unsigned short)(u >> 16);
}

// ws layout (floats): [0]=hinge sum, [1]=abs sum, [2]=sq sum, [16..16+1024)=colsum
// byte offset 8192: wbfT bf16 [1024][1024]  (wbfT[n][k] = w[k][n])

__global__ __launch_bounds__(256) void prep_w(const float* __restrict__ w,
                                              float* __restrict__ wsf,
                                              unsigned short* __restrict__ wbfT) {
  __shared__ unsigned short tile[32][34];
  __shared__ float csum[32];
  const int t = threadIdx.x;
  const int ti = blockIdx.x & 31;   // row-tile of w (k)
  const int tj = blockIdx.x >> 5;   // col-tile of w (n)
  const int r = t >> 5;             // 0..7
  const int c = t & 31;
  if (t < 32) csum[t] = 0.f;
  __syncthreads();
  float colpart = 0.f, aacc = 0.f, sacc = 0.f;
#pragma unroll
  for (int q = 0; q < 4; ++q) {
    const int row = r + q * 8;
    const int gi = ti * 32 + row;
    const int gj = tj * 32 + c;
    const float v = w[gi * FDIM + gj];
    tile[row][c] = f2bf(v);
    colpart += v;
    const float dv = v - (gi == gj ? 1.f : 0.f);
    aacc += fabsf(dv);
    sacc += dv * dv;
  }
  atomicAdd(&csum[c], colpart);
#pragma unroll
  for (int off = 1; off < 64; off <<= 1) {
    aacc += __shfl_xor(aacc, off);
    sacc += __shfl_xor(sacc, off);
  }
  if ((t & 63) == 0) {
    atomicAdd(&wsf[1], aacc);
    atomicAdd(&wsf[2], sacc);
  }
  __syncthreads();
  if (t < 32) atomicAdd(&wsf[16 + tj * 32 + t], csum[t]);
#pragma unroll
  for (int q = 0; q < 4; ++q) {
    const int orow = r + q * 8;
    // wbfT[n = tj*32+orow][k = ti*32+c] = w[k][n]
    wbfT[(tj * 32 + orow) * FDIM + ti * 32 + c] = tile[c][orow];
  }
}

#define LDSA_PITCH 1032
#define LDSB_PITCH 40
#define SMEM_A_BYTES (64 * LDSA_PITCH * 2)
#define SMEM_B_BYTES (256 * LDSB_PITCH * 2)
#define SMEM_BYTES (SMEM_A_BYTES + SMEM_B_BYTES + 4096 + 256)

__global__ __launch_bounds__(1024, 4) void hofel_main(
    const float* __restrict__ skt, const float* __restrict__ imgp,
    const float* __restrict__ imgn, const unsigned short* __restrict__ wbfT,
    const float* __restrict__ colsum, float* __restrict__ hinge_acc) {
  extern __shared__ char smem[];
  unsigned short* ldsA = (unsigned short*)smem;                       // [64][1032]
  unsigned short* ldsB = (unsigned short*)(smem + SMEM_A_BYTES);      // [256][40]
  float* lds_cs = (float*)(smem + SMEM_A_BYTES + SMEM_B_BYTES);       // [1024]
  float* lds_c  = (float*)(smem + SMEM_A_BYTES + SMEM_B_BYTES + 4096);// [64]

  const int t = threadIdx.x;
  const int lane = t & 63;
  const int wid = t >> 6;
  const int m0 = blockIdx.x * 64;
  const int l15 = lane & 15;
  const int l4 = lane >> 4;  // 0..3

  if (t < 64) lds_c[t] = 0.f;
  lds_cs[t] = colsum[t];

  // stage A: skt[m0..m0+64][:] -> bf16 LDS (read once, coalesced float4)
#pragma unroll 4
  for (int p = 0; p < 16; ++p) {
    const int id = p * 1024 + t;
    const int row = id >> 8;              // 0..63
    const int col4 = (id & 255) << 2;     // 0..1020
    const float4 v = *(const float4*)(skt + (m0 + row) * FDIM + col4);
    ushort4 bb;
    bb.x = f2bf(v.x); bb.y = f2bf(v.y); bb.z = f2bf(v.z); bb.w = f2bf(v.w);
    *(ushort4*)(ldsA + row * LDSA_PITCH + col4) = bb;
  }

  const int mg = wid >> 3;  // 0..1  (32-row group)
  const int ng = wid & 7;   // 0..7  (32-col group within 256-col chunk)

  // W staging assignment: thread -> (row bc of 256-col chunk, 16B k-segment)
  const int bc = t >> 2;        // 0..255
  const int bk = (t & 3) * 8;   // elem offset in k-slice (8 bf16 = 16B)
  int4 bReg = *(const int4*)(wbfT + bc * FDIM + bk);  // prefetch j=0,k=0

  f4v acc[2][2];

  for (int j = 0; j < 4; ++j) {
    const int j0 = j * 256;
#pragma unroll
    for (int mt = 0; mt < 2; ++mt)
#pragma unroll
      for (int nt = 0; nt < 2; ++nt) {
        f4v z = {0.f, 0.f, 0.f, 0.f};
        acc[mt][nt] = z;
      }

    for (int k = 0; k < 32; ++k) {
      __syncthreads();                                   // LDS consumers done
      *(int4*)(ldsB + bc * LDSB_PITCH + bk) = bReg;      // k-slice -> LDS
      __syncthreads();                                   // slice ready
      if (k < 31)
        bReg = *(const int4*)(wbfT + (j0 + bc) * FDIM + (k + 1) * 32 + bk);
      else if (j < 3)
        bReg = *(const int4*)(wbfT + (j0 + 256 + bc) * FDIM + bk);

      const int ko = l4 * 8;
      const bf8v aF0 = *(const bf8v*)(ldsA + (mg * 32 + l15) * LDSA_PITCH + k * 32 + ko);
      const bf8v aF1 = *(const bf8v*)(ldsA + (mg * 32 + 16 + l15) * LDSA_PITCH + k * 32 + ko);
#pragma unroll
      for (int nt = 0; nt < 2; ++nt) {
        const bf8v bF = *(const bf8v*)(ldsB + (ng * 32 + nt * 16 + l15) * LDSB_PITCH + ko);
        acc[0][nt] = __builtin_amdgcn_mfma_f32_16x16x32_bf16(aF0, bF, acc[0][nt], 0, 0, 0);
        acc[1][nt] = __builtin_amdgcn_mfma_f32_16x16x32_bf16(aF1, bF, acc[1][nt], 0, 0, 0);
      }
    }

    // fused epilogue for this 256-col chunk:
    // contrib[b] += (p-n) * (-2*T + (p+n)*colsum[c])
#pragma unroll
    for (int mt = 0; mt < 2; ++mt) {
#pragma unroll
      for (int rg = 0; rg < 4; ++rg) {
        const int rloc = mg * 32 + mt * 16 + l4 * 4 + rg;  // C/D: row=(lane>>4)*4+reg
        const int grow = (m0 + rloc) * FDIM;
        float sum = 0.f;
#pragma unroll
        for (int nt = 0; nt < 2; ++nt) {
          const int c = j0 + ng * 32 + nt * 16 + l15;      // C/D: col=lane&15
          const float T = acc[mt][nt][rg];
          const float p = imgp[grow + c];
          const float n = imgn[grow + c];
          sum += (p - n) * (-2.f * T + (p + n) * lds_cs[c]);
        }
#pragma unroll
        for (int off = 1; off < 16; off <<= 1) sum += __shfl_xor(sum, off);
        if (l15 == 0) atomicAdd(&lds_c[rloc], sum);
      }
    }
  }

  __syncthreads();
  if (t < 64) {
    float v = fmaxf(DELTA_C + lds_c[t], 0.f);
#pragma unroll
    for (int off = 1; off < 64; off <<= 1) v += __shfl_xor(v, off);
    if (t == 0) atomicAdd(hinge_acc, v);
  }
}

__global__ void finalize_k(const float* __restrict__ wsf, float* __restrict__ out) {
  if (threadIdx.x == 0)
    out[0] = wsf[0] * (1.f / (float)BROWS) + LAMB_C * (wsf[1] + sqrtf(wsf[2]));
}

extern "C" void kernel_launch(void* const* d_in, const int* in_sizes, int n_in,
                              void* d_out, int out_size, void* d_ws, size_t ws_size,
                              hipStream_t stream) {
  const float* skt  = (const float*)d_in[0];
  const float* imgp = (const float*)d_in[1];
  const float* imgn = (const float*)d_in[2];
  const float* w    = (const float*)d_in[3];
  // d_in[4] = eye (identity by construction; folded into prep_w)

  float* wsf = (float*)d_ws;
  unsigned short* wbfT = (unsigned short*)((char*)d_ws + 8192);
  float* out = (float*)d_out;

  // zero accumulators + colsum region (re-done every call: harness doesn't re-poison)
  hipMemsetAsync(d_ws, 0, 8192, stream);

  prep_w<<<1024, 256, 0, stream>>>(w, wsf, wbfT);

  (void)hipFuncSetAttribute(reinterpret_cast<const void*>(hofel_main),
                            hipFuncAttributeMaxDynamicSharedMemorySize, SMEM_BYTES);
  hofel_main<<<256, 1024, SMEM_BYTES, stream>>>(skt, imgp, imgn, wbfT, wsf + 16, wsf);

  finalize_k<<<1, 64, 0, stream>>>(wsf, out);
}

// Round 2
// 183.089 us; speedup vs baseline: 1.1652x; 1.1652x over previous
//
#include <hip/hip_runtime.h>
#include <hip/hip_bf16.h>

#define FDIM 1024
#define BROWS 16384
#define DELTA_C 0.3f
#define LAMB_C 0.0005f

typedef __bf16 bf8v __attribute__((ext_vector_type(8)));
typedef float f4v __attribute__((ext_vector_type(4)));
typedef unsigned short u16;
typedef u16 u16x8 __attribute__((ext_vector_type(8)));

// ws layout (bytes):
//   0      : f32 wsf[16]   (0=hinge, 1=abs, 2=sq)
//   64     : f32 colsum[1024]          (wsf+16)
//   8192   : f32 rowacc[16384]  (64KB)
//   131072 : wb  bf16 tiled [128 kslot][1024 n][8]   (2MB)   wb[((ks)*1024+n)*8+e] = w[ks*8+e][n]
//   131072+2MB : sktb bf16 tiled [128 kslot][16384 m][8] (32MB)
#define WS_ROWACC_OFF 8192
#define WS_WB_OFF 131072
#define WS_SKTB_OFF (131072 + (1u << 21))
#define WS_NEED_FULL ((size_t)WS_SKTB_OFF + ((size_t)1 << 25))

__device__ __forceinline__ u16 f2bf(float f) {
  unsigned u = __builtin_bit_cast(unsigned, f);
  u += 0x7fffu + ((u >> 16) & 1u);
  return (u16)(u >> 16);
}

__device__ __forceinline__ void gload_lds16(const void* g, void* l) {
  __builtin_amdgcn_global_load_lds(
      (const __attribute__((address_space(1))) unsigned int*)g,
      (__attribute__((address_space(3))) unsigned int*)l, 16, 0, 0);
}

// ---- prep W: colsum, |w-I| sums, and bf16 tiled transpose ----
__global__ __launch_bounds__(256) void prep_w(const float* __restrict__ w,
                                              float* __restrict__ wsf,
                                              u16* __restrict__ wb) {
  __shared__ u16 tile[32][34];  // [k_local][n_local]
  __shared__ float csum[32];
  const int t = threadIdx.x;
  const int ti = blockIdx.x & 31;  // k-tile
  const int tj = blockIdx.x >> 5;  // n-tile
  const int r = t >> 5;            // 0..7
  const int c = t & 31;
  if (t < 32) csum[t] = 0.f;
  __syncthreads();
  float colpart = 0.f, aacc = 0.f, sacc = 0.f;
#pragma unroll
  for (int q = 0; q < 4; ++q) {
    const int kl = r + q * 8;
    const int gk = ti * 32 + kl;
    const int gn = tj * 32 + c;
    const float v = w[gk * FDIM + gn];
    tile[kl][c] = f2bf(v);
    colpart += v;
    const float dv = v - (gk == gn ? 1.f : 0.f);
    aacc += fabsf(dv);
    sacc += dv * dv;
  }
  atomicAdd(&csum[c], colpart);
#pragma unroll
  for (int off = 1; off < 64; off <<= 1) {
    aacc += __shfl_xor(aacc, off);
    sacc += __shfl_xor(sacc, off);
  }
  if ((t & 63) == 0) {
    atomicAdd(&wsf[1], aacc);
    atomicAdd(&wsf[2], sacc);
  }
  __syncthreads();
  if (t < 32) atomicAdd(&wsf[16 + tj * 32 + t], csum[t]);
  if (t < 128) {
    const int si = t >> 5;  // 0..3 (kslot within tile)
    const int nl = t & 31;
    u16x8 pk;
#pragma unroll
    for (int e = 0; e < 8; ++e) pk[e] = tile[si * 8 + e][nl];
    *(u16x8*)(wb + ((size_t)(ti * 4 + si) * FDIM + tj * 32 + nl) * 8) = pk;
  }
}

// ---- prep A: f32 -> bf16, tiled [kslot][m][8] ----
__global__ __launch_bounds__(256) void prep_a(const float* __restrict__ skt,
                                              u16* __restrict__ sktb) {
  __shared__ u16 tile[64][136];  // pitch 272B (16B-aligned rows)
  const int t = threadIdx.x;
  const int mb = blockIdx.x >> 3;  // 0..255
  const int kb = blockIdx.x & 7;   // 0..7
  const int m0 = mb * 64, k0 = kb * 128;
#pragma unroll
  for (int i = 0; i < 8; ++i) {
    const int fid = i * 256 + t;
    const int ml = fid >> 5;
    const int c4 = fid & 31;
    const float4 v = *(const float4*)(skt + (size_t)(m0 + ml) * FDIM + k0 + c4 * 4);
    ushort4 b;
    b.x = f2bf(v.x); b.y = f2bf(v.y); b.z = f2bf(v.z); b.w = f2bf(v.w);
    *(ushort4*)(&tile[ml][c4 * 4]) = b;
  }
  __syncthreads();
  const int ks0 = k0 >> 3;
#pragma unroll
  for (int i = 0; i < 4; ++i) {
    const int uid = i * 256 + t;
    const int si = uid >> 6;  // 0..15
    const int ml = uid & 63;
    const u16x8 pk = *(const u16x8*)(&tile[ml][si * 8]);
    *(u16x8*)(sktb + ((size_t)(ks0 + si) * BROWS + m0 + ml) * 8) = pk;
  }
}

// ---- main: T = skt @ w (bf16 MFMA), fused distance epilogue ----
template <bool PRE>
__global__ __launch_bounds__(256, 3) void hofel_main(
    const float* __restrict__ skt, const float* __restrict__ imgp,
    const float* __restrict__ imgn, const u16* __restrict__ wb,
    const u16* __restrict__ sktb, const float* __restrict__ colsum,
    float* __restrict__ rowacc) {
  __shared__ u16 ldsT[8192];  // A: bytes [0,8K) = [4][128][8]; B: [8K,16K)
  __shared__ float lds_cs[128];

  const int t = threadIdx.x;
  const int lane = t & 63;
  const int wid = t >> 6;
  const int l15 = lane & 15;
  const int l4 = lane >> 4;

  // XCD-aware swizzle (1024 % 8 == 0, bijective): XCD x gets mt in [x*16, x*16+16)
  const int swz = (blockIdx.x & 7) * 128 + (blockIdx.x >> 3);
  const int mt = swz >> 3, nt = swz & 7;
  const int m0 = mt * 128, n0 = nt * 128;

  if (t < 128) lds_cs[t] = colsum[n0 + t];

  const int wm = (wid >> 1) * 64;  // wave row offset
  const int wn = (wid & 1) * 64;   // wave col offset

  f4v acc[4][4];
#pragma unroll
  for (int mi = 0; mi < 4; ++mi)
#pragma unroll
    for (int ni = 0; ni < 4; ++ni) {
      f4v z = {0.f, 0.f, 0.f, 0.f};
      acc[mi][ni] = z;
    }

  for (int kt = 0; kt < 32; ++kt) {
    __syncthreads();  // all waves done reading previous tiles
    if constexpr (PRE) {
#pragma unroll
      for (int r = 0; r < 4; ++r) {
        const int o = r * 4096 + wid * 1024;  // wave-uniform LDS byte base
        const int ol = o + lane * 16;
        const char* src;
        if (ol < 8192) {  // A region
          const int s = ol >> 11;
          const int m = (ol >> 4) & 127;
          src = (const char*)(sktb + ((size_t)(kt * 4 + s) * BROWS + m0 + m) * 8);
        } else {  // B region
          const int o2 = ol - 8192;
          const int s = o2 >> 11;
          const int n = (o2 >> 4) & 127;
          src = (const char*)(wb + ((size_t)(kt * 4 + s) * FDIM + n0 + n) * 8);
        }
        gload_lds16(src, (char*)ldsT + o);
      }
    } else {
      // B via global_load_lds (2 rounds)
#pragma unroll
      for (int r = 0; r < 2; ++r) {
        const int o = r * 4096 + wid * 1024;
        const int ol = o + lane * 16;
        const int s = ol >> 11;
        const int n = (ol >> 4) & 127;
        gload_lds16((const char*)(wb + ((size_t)(kt * 4 + s) * FDIM + n0 + n) * 8),
                    (char*)ldsT + 8192 + o);
      }
      // A: f32 load + convert + ds_write
      const int m = t >> 1, h = t & 1;
      const float* ap = skt + (size_t)(m0 + m) * FDIM + kt * 32 + h * 16;
      const float4 v0 = *(const float4*)(ap);
      const float4 v1 = *(const float4*)(ap + 4);
      const float4 v2 = *(const float4*)(ap + 8);
      const float4 v3 = *(const float4*)(ap + 12);
      u16x8 w0, w1;
      w0[0] = f2bf(v0.x); w0[1] = f2bf(v0.y); w0[2] = f2bf(v0.z); w0[3] = f2bf(v0.w);
      w0[4] = f2bf(v1.x); w0[5] = f2bf(v1.y); w0[6] = f2bf(v1.z); w0[7] = f2bf(v1.w);
      w1[0] = f2bf(v2.x); w1[1] = f2bf(v2.y); w1[2] = f2bf(v2.z); w1[3] = f2bf(v2.w);
      w1[4] = f2bf(v3.x); w1[5] = f2bf(v3.y); w1[6] = f2bf(v3.z); w1[7] = f2bf(v3.w);
      *(u16x8*)((char*)ldsT + ((h * 2) * 128 + m) * 16) = w0;
      *(u16x8*)((char*)ldsT + ((h * 2 + 1) * 128 + m) * 16) = w1;
    }
    __syncthreads();  // staging visible (compiler drains vmcnt/lgkm before barrier)

    bf8v aF[4], bF[4];
#pragma unroll
    for (int mi = 0; mi < 4; ++mi)
      aF[mi] = *(const bf8v*)((char*)ldsT + ((l4 * 128) + wm + mi * 16 + l15) * 16);
#pragma unroll
    for (int ni = 0; ni < 4; ++ni)
      bF[ni] = *(const bf8v*)((char*)ldsT + 8192 + ((l4 * 128) + wn + ni * 16 + l15) * 16);
#pragma unroll
    for (int mi = 0; mi < 4; ++mi)
#pragma unroll
      for (int ni = 0; ni < 4; ++ni)
        acc[mi][ni] = __builtin_amdgcn_mfma_f32_16x16x32_bf16(aF[mi], bF[ni], acc[mi][ni], 0, 0, 0);
  }

  // fused epilogue: rowacc[row] += sum_c (p-n)*(-2*T + (p+n)*colsum[c])
#pragma unroll
  for (int mi = 0; mi < 4; ++mi) {
#pragma unroll
    for (int rr = 0; rr < 4; ++rr) {
      const int row = m0 + wm + mi * 16 + l4 * 4 + rr;
      const float* pr = imgp + (size_t)row * FDIM + n0;
      const float* nr = imgn + (size_t)row * FDIM + n0;
      float s = 0.f;
#pragma unroll
      for (int ni = 0; ni < 4; ++ni) {
        const int cl = wn + ni * 16 + l15;
        const float T = acc[mi][ni][rr];
        const float p = pr[cl];
        const float q = nr[cl];
        s += (p - q) * (-2.f * T + (p + q) * lds_cs[cl]);
      }
#pragma unroll
      for (int off = 1; off < 16; off <<= 1) s += __shfl_xor(s, off);
      if (l15 == 0) atomicAdd(rowacc + row, s);
    }
  }
}

__global__ __launch_bounds__(1024) void hinge_reduce(const float* __restrict__ rowacc,
                                                     float* __restrict__ wsf) {
  __shared__ float part[16];
  const int t = threadIdx.x;
  const int id = blockIdx.x * 1024 + t;
  float v = fmaxf(DELTA_C + rowacc[id], 0.f);
#pragma unroll
  for (int off = 1; off < 64; off <<= 1) v += __shfl_xor(v, off);
  if ((t & 63) == 0) part[t >> 6] = v;
  __syncthreads();
  if (t < 16) {
    float x = part[t];
#pragma unroll
    for (int off = 1; off < 16; off <<= 1) x += __shfl_xor(x, off);
    if (t == 0) atomicAdd(&wsf[0], x);
  }
}

__global__ void finalize_k(const float* __restrict__ wsf, float* __restrict__ out) {
  if (threadIdx.x == 0)
    out[0] = wsf[0] * (1.f / (float)BROWS) + LAMB_C * (wsf[1] + sqrtf(wsf[2]));
}

extern "C" void kernel_launch(void* const* d_in, const int* in_sizes, int n_in,
                              void* d_out, int out_size, void* d_ws, size_t ws_size,
                              hipStream_t stream) {
  const float* skt  = (const float*)d_in[0];
  const float* imgp = (const float*)d_in[1];
  const float* imgn = (const float*)d_in[2];
  const float* w    = (const float*)d_in[3];

  float* wsf = (float*)d_ws;
  float* rowacc = (float*)((char*)d_ws + WS_ROWACC_OFF);
  u16* wb = (u16*)((char*)d_ws + WS_WB_OFF);
  u16* sktb = (u16*)((char*)d_ws + WS_SKTB_OFF);
  float* out = (float*)d_out;

  // zero wsf + colsum + rowacc every call (harness doesn't re-poison)
  hipMemsetAsync(d_ws, 0, WS_ROWACC_OFF + BROWS * sizeof(float), stream);

  prep_w<<<1024, 256, 0, stream>>>(w, wsf, wb);

  if (ws_size >= WS_NEED_FULL) {
    prep_a<<<2048, 256, 0, stream>>>(skt, sktb);
    hofel_main<true><<<1024, 256, 0, stream>>>(skt, imgp, imgn, wb, sktb, wsf + 16, rowacc);
  } else {
    hofel_main<false><<<1024, 256, 0, stream>>>(skt, imgp, imgn, wb, sktb, wsf + 16, rowacc);
  }

  hinge_reduce<<<16, 1024, 0, stream>>>(rowacc, wsf);
  finalize_k<<<1, 64, 0, stream>>>(wsf, out);
}

// Round 3
// 93.184 us; speedup vs baseline: 2.2894x; 1.9648x over previous
//
#include <hip/hip_runtime.h>
#include <hip/hip_bf16.h>

#define FDIM 1024
#define BROWS 16384
#define DELTA_C 0.3f
#define LAMB_C 0.0005f

typedef __bf16 bf8v __attribute__((ext_vector_type(8)));
typedef float f4v __attribute__((ext_vector_type(4)));
typedef unsigned short u16;
typedef u16 u16x8 __attribute__((ext_vector_type(8)));

// ws layout (bytes):
//   0    : f32 wsf[16]     (0=hinge)
//   64   : f32 colsum[1024]  (wsf+16)
//   4160 : f32 pabs[128]
//   4672 : f32 psq[128]
//   8192 : f32 rowacc[16384]  (64KB)
//   131072 : wb  bf16 tiled [128 kslot][1024 n][8]   (2MB)  wb[(ks*1024+n)*8+e] = w[ks*8+e][n]
//   131072+2MB : sktb bf16 tiled [2048 kslot][16384 m][8]... (32MB) sktb[(ks*16384+m)*8+e] = skt[m][ks*8+e]
#define WS_PABS_OFF 4160
#define WS_PSQ_OFF 4672
#define WS_ROWACC_OFF 8192
#define WS_WB_OFF 131072
#define WS_SKTB_OFF (131072 + (1u << 21))
#define WS_NEED_FULL ((size_t)WS_SKTB_OFF + ((size_t)1 << 25))

__device__ __forceinline__ u16 f2bf(float f) {
  unsigned u = __builtin_bit_cast(unsigned, f);
  u += 0x7fffu + ((u >> 16) & 1u);
  return (u16)(u >> 16);
}

__device__ __forceinline__ void gload_lds16(const void* g, void* l) {
  __builtin_amdgcn_global_load_lds(
      (const __attribute__((address_space(1))) unsigned int*)g,
      (__attribute__((address_space(3))) unsigned int*)l, 16, 0, 0);
}

// ---- prep W: colsum, |w-I| block partials, bf16 tiled transpose ----
// 128 blocks; block b owns k-rows [b*8, b*8+8) == kslot b.
__global__ __launch_bounds__(256) void prep_w(const float* __restrict__ w,
                                              float* __restrict__ colsum,
                                              float* __restrict__ pabs,
                                              float* __restrict__ psq,
                                              u16* __restrict__ wb) {
  __shared__ u16 tile[8][1024];  // 16KB bf16 staging
  __shared__ float red[8];
  const int t = threadIdx.x;
  const int b = blockIdx.x;
  const int k0 = b * 8;
  const int col = t * 4;  // this thread owns columns col..col+3 across all 8 rows

  float cs0 = 0.f, cs1 = 0.f, cs2 = 0.f, cs3 = 0.f;
  float aacc = 0.f, sacc = 0.f;
#pragma unroll
  for (int i = 0; i < 8; ++i) {
    const int gk = k0 + i;
    const float4 v = *(const float4*)(w + (size_t)gk * FDIM + col);
    ushort4 bb;
    bb.x = f2bf(v.x); bb.y = f2bf(v.y); bb.z = f2bf(v.z); bb.w = f2bf(v.w);
    *(ushort4*)(&tile[i][col]) = bb;
    cs0 += v.x; cs1 += v.y; cs2 += v.z; cs3 += v.w;
    const float d0 = v.x - (gk == col + 0 ? 1.f : 0.f);
    const float d1 = v.y - (gk == col + 1 ? 1.f : 0.f);
    const float d2 = v.z - (gk == col + 2 ? 1.f : 0.f);
    const float d3 = v.w - (gk == col + 3 ? 1.f : 0.f);
    aacc += fabsf(d0) + fabsf(d1) + fabsf(d2) + fabsf(d3);
    sacc += d0 * d0 + d1 * d1 + d2 * d2 + d3 * d3;
  }
  // colsum: distinct addresses, 128 adds per address across grid
  atomicAdd(&colsum[col + 0], cs0);
  atomicAdd(&colsum[col + 1], cs1);
  atomicAdd(&colsum[col + 2], cs2);
  atomicAdd(&colsum[col + 3], cs3);
  // abs/sq: wave reduce -> LDS -> single store per block (no global atomics)
#pragma unroll
  for (int off = 1; off < 64; off <<= 1) {
    aacc += __shfl_xor(aacc, off);
    sacc += __shfl_xor(sacc, off);
  }
  const int wid = t >> 6;
  if ((t & 63) == 0) { red[wid] = aacc; red[4 + wid] = sacc; }
  __syncthreads();
  if (t == 0) pabs[b] = red[0] + red[1] + red[2] + red[3];
  if (t == 1) psq[b] = red[4] + red[5] + red[6] + red[7];
  // transpose write: wb[(b*1024 + n)*8 + e] = tile[e][n]
#pragma unroll
  for (int j = 0; j < 4; ++j) {
    const int n = col + j;
    u16x8 pk;
#pragma unroll
    for (int e = 0; e < 8; ++e) pk[e] = tile[e][n];
    *(u16x8*)(wb + ((size_t)b * FDIM + n) * 8) = pk;
  }
}

// ---- prep A: f32 -> bf16, tiled [kslot][m][8] ----
__global__ __launch_bounds__(256) void prep_a(const float* __restrict__ skt,
                                              u16* __restrict__ sktb) {
  __shared__ u16 tile[64][136];  // pitch 272B
  const int t = threadIdx.x;
  const int mb = blockIdx.x >> 3;
  const int kb = blockIdx.x & 7;
  const int m0 = mb * 64, k0 = kb * 128;
#pragma unroll
  for (int i = 0; i < 8; ++i) {
    const int fid = i * 256 + t;
    const int ml = fid >> 5;
    const int c4 = fid & 31;
    const float4 v = *(const float4*)(skt + (size_t)(m0 + ml) * FDIM + k0 + c4 * 4);
    ushort4 b;
    b.x = f2bf(v.x); b.y = f2bf(v.y); b.z = f2bf(v.z); b.w = f2bf(v.w);
    *(ushort4*)(&tile[ml][c4 * 4]) = b;
  }
  __syncthreads();
  const int ks0 = k0 >> 3;
#pragma unroll
  for (int i = 0; i < 4; ++i) {
    const int uid = i * 256 + t;
    const int si = uid >> 6;
    const int ml = uid & 63;
    const u16x8 pk = *(const u16x8*)(&tile[ml][si * 8]);
    *(u16x8*)(sktb + ((size_t)(ks0 + si) * BROWS + m0 + ml) * 8) = pk;
  }
}

// ---- main: T = skt @ w (bf16 MFMA), fused distance epilogue ----
template <bool PRE>
__global__ __launch_bounds__(256, 3) void hofel_main(
    const float* __restrict__ skt, const float* __restrict__ imgp,
    const float* __restrict__ imgn, const u16* __restrict__ wb,
    const u16* __restrict__ sktb, const float* __restrict__ colsum,
    float* __restrict__ rowacc) {
  __shared__ u16 ldsT[8192];  // A: bytes [0,8K) = [4][128][8]; B: [8K,16K)
  __shared__ float lds_cs[128];

  const int t = threadIdx.x;
  const int lane = t & 63;
  const int wid = t >> 6;
  const int l15 = lane & 15;
  const int l4 = lane >> 4;

  const int swz = (blockIdx.x & 7) * 128 + (blockIdx.x >> 3);
  const int mt = swz >> 3, nt = swz & 7;
  const int m0 = mt * 128, n0 = nt * 128;

  if (t < 128) lds_cs[t] = colsum[n0 + t];

  const int wm = (wid >> 1) * 64;
  const int wn = (wid & 1) * 64;

  f4v acc[4][4];
#pragma unroll
  for (int mi = 0; mi < 4; ++mi)
#pragma unroll
    for (int ni = 0; ni < 4; ++ni) {
      f4v z = {0.f, 0.f, 0.f, 0.f};
      acc[mi][ni] = z;
    }

  for (int kt = 0; kt < 32; ++kt) {
    __syncthreads();
    if constexpr (PRE) {
#pragma unroll
      for (int r = 0; r < 4; ++r) {
        const int o = r * 4096 + wid * 1024;
        const int ol = o + lane * 16;
        const char* src;
        if (ol < 8192) {
          const int s = ol >> 11;
          const int m = (ol >> 4) & 127;
          src = (const char*)(sktb + ((size_t)(kt * 4 + s) * BROWS + m0 + m) * 8);
        } else {
          const int o2 = ol - 8192;
          const int s = o2 >> 11;
          const int n = (o2 >> 4) & 127;
          src = (const char*)(wb + ((size_t)(kt * 4 + s) * FDIM + n0 + n) * 8);
        }
        gload_lds16(src, (char*)ldsT + o);
      }
    } else {
#pragma unroll
      for (int r = 0; r < 2; ++r) {
        const int o = r * 4096 + wid * 1024;
        const int ol = o + lane * 16;
        const int s = ol >> 11;
        const int n = (ol >> 4) & 127;
        gload_lds16((const char*)(wb + ((size_t)(kt * 4 + s) * FDIM + n0 + n) * 8),
                    (char*)ldsT + 8192 + o);
      }
      const int m = t >> 1, h = t & 1;
      const float* ap = skt + (size_t)(m0 + m) * FDIM + kt * 32 + h * 16;
      const float4 v0 = *(const float4*)(ap);
      const float4 v1 = *(const float4*)(ap + 4);
      const float4 v2 = *(const float4*)(ap + 8);
      const float4 v3 = *(const float4*)(ap + 12);
      u16x8 w0, w1;
      w0[0] = f2bf(v0.x); w0[1] = f2bf(v0.y); w0[2] = f2bf(v0.z); w0[3] = f2bf(v0.w);
      w0[4] = f2bf(v1.x); w0[5] = f2bf(v1.y); w0[6] = f2bf(v1.z); w0[7] = f2bf(v1.w);
      w1[0] = f2bf(v2.x); w1[1] = f2bf(v2.y); w1[2] = f2bf(v2.z); w1[3] = f2bf(v2.w);
      w1[4] = f2bf(v3.x); w1[5] = f2bf(v3.y); w1[6] = f2bf(v3.z); w1[7] = f2bf(v3.w);
      *(u16x8*)((char*)ldsT + ((h * 2) * 128 + m) * 16) = w0;
      *(u16x8*)((char*)ldsT + ((h * 2 + 1) * 128 + m) * 16) = w1;
    }
    __syncthreads();

    bf8v aF[4], bF[4];
#pragma unroll
    for (int mi = 0; mi < 4; ++mi)
      aF[mi] = *(const bf8v*)((char*)ldsT + ((l4 * 128) + wm + mi * 16 + l15) * 16);
#pragma unroll
    for (int ni = 0; ni < 4; ++ni)
      bF[ni] = *(const bf8v*)((char*)ldsT + 8192 + ((l4 * 128) + wn + ni * 16 + l15) * 16);
#pragma unroll
    for (int mi = 0; mi < 4; ++mi)
#pragma unroll
      for (int ni = 0; ni < 4; ++ni)
        acc[mi][ni] = __builtin_amdgcn_mfma_f32_16x16x32_bf16(aF[mi], bF[ni], acc[mi][ni], 0, 0, 0);
  }

#pragma unroll
  for (int mi = 0; mi < 4; ++mi) {
#pragma unroll
    for (int rr = 0; rr < 4; ++rr) {
      const int row = m0 + wm + mi * 16 + l4 * 4 + rr;
      const float* pr = imgp + (size_t)row * FDIM + n0;
      const float* nr = imgn + (size_t)row * FDIM + n0;
      float s = 0.f;
#pragma unroll
      for (int ni = 0; ni < 4; ++ni) {
        const int cl = wn + ni * 16 + l15;
        const float T = acc[mi][ni][rr];
        const float p = pr[cl];
        const float q = nr[cl];
        s += (p - q) * (-2.f * T + (p + q) * lds_cs[cl]);
      }
#pragma unroll
      for (int off = 1; off < 16; off <<= 1) s += __shfl_xor(s, off);
      if (l15 == 0) atomicAdd(rowacc + row, s);
    }
  }
}

__global__ __launch_bounds__(1024) void hinge_reduce(const float* __restrict__ rowacc,
                                                     float* __restrict__ wsf) {
  __shared__ float part[16];
  const int t = threadIdx.x;
  const int id = blockIdx.x * 1024 + t;
  float v = fmaxf(DELTA_C + rowacc[id], 0.f);
#pragma unroll
  for (int off = 1; off < 64; off <<= 1) v += __shfl_xor(v, off);
  if ((t & 63) == 0) part[t >> 6] = v;
  __syncthreads();
  if (t < 16) {
    float x = part[t];
#pragma unroll
    for (int off = 1; off < 16; off <<= 1) x += __shfl_xor(x, off);
    if (t == 0) atomicAdd(&wsf[0], x);
  }
}

__global__ __launch_bounds__(128) void finalize_k(const float* __restrict__ wsf,
                                                  const float* __restrict__ pabs,
                                                  const float* __restrict__ psq,
                                                  float* __restrict__ out) {
  __shared__ float ra[2], rs[2];
  const int t = threadIdx.x;
  float a = pabs[t], s = psq[t];
#pragma unroll
  for (int off = 1; off < 64; off <<= 1) {
    a += __shfl_xor(a, off);
    s += __shfl_xor(s, off);
  }
  if ((t & 63) == 0) { ra[t >> 6] = a; rs[t >> 6] = s; }
  __syncthreads();
  if (t == 0)
    out[0] = wsf[0] * (1.f / (float)BROWS) +
             LAMB_C * ((ra[0] + ra[1]) + sqrtf(rs[0] + rs[1]));
}

extern "C" void kernel_launch(void* const* d_in, const int* in_sizes, int n_in,
                              void* d_out, int out_size, void* d_ws, size_t ws_size,
                              hipStream_t stream) {
  const float* skt  = (const float*)d_in[0];
  const float* imgp = (const float*)d_in[1];
  const float* imgn = (const float*)d_in[2];
  const float* w    = (const float*)d_in[3];

  float* wsf = (float*)d_ws;
  float* colsum = wsf + 16;
  float* pabs = (float*)((char*)d_ws + WS_PABS_OFF);
  float* psq = (float*)((char*)d_ws + WS_PSQ_OFF);
  float* rowacc = (float*)((char*)d_ws + WS_ROWACC_OFF);
  u16* wb = (u16*)((char*)d_ws + WS_WB_OFF);
  u16* sktb = (u16*)((char*)d_ws + WS_SKTB_OFF);
  float* out = (float*)d_out;

  // zero wsf + colsum + rowacc every call (harness doesn't re-poison)
  hipMemsetAsync(d_ws, 0, WS_ROWACC_OFF + BROWS * sizeof(float), stream);

  prep_w<<<128, 256, 0, stream>>>(w, colsum, pabs, psq, wb);

  if (ws_size >= WS_NEED_FULL) {
    prep_a<<<2048, 256, 0, stream>>>(skt, sktb);
    hofel_main<true><<<1024, 256, 0, stream>>>(skt, imgp, imgn, wb, sktb, colsum, rowacc);
  } else {
    hofel_main<false><<<1024, 256, 0, stream>>>(skt, imgp, imgn, wb, sktb, colsum, rowacc);
  }

  hinge_reduce<<<16, 1024, 0, stream>>>(rowacc, wsf);
  finalize_k<<<1, 128, 0, stream>>>(wsf, pabs, psq, out);
}

// Round 4
// 88.625 us; speedup vs baseline: 2.4072x; 1.0514x over previous
//
#include <hip/hip_runtime.h>
#include <hip/hip_bf16.h>

#define FDIM 1024
#define BROWS 16384
#define DELTA_C 0.3f
#define LAMB_C 0.0005f

typedef __bf16 bf8v __attribute__((ext_vector_type(8)));
typedef float f4v __attribute__((ext_vector_type(4)));
typedef unsigned short u16;
typedef u16 u16x8 __attribute__((ext_vector_type(8)));

// ws layout (bytes):
//   0    : f32 wsf[16]     (0=hinge)
//   64   : f32 colsum[1024]  (wsf+16)
//   4160 : f32 pabs[128]
//   4672 : f32 psq[128]
//   8192 : f32 rowacc[16384]  (64KB)
//   131072 : wb  bf16 tiled [128 kslot][1024 n][8]   (2MB)  wb[(ks*1024+n)*8+e] = w[ks*8+e][n]
//   131072+2MB : sktb bf16 tiled [128 kslot][16384 m][8] (32MB) sktb[(ks*16384+m)*8+e] = skt[m][ks*8+e]
#define WS_PABS_OFF 4160
#define WS_PSQ_OFF 4672
#define WS_ROWACC_OFF 8192
#define WS_WB_OFF 131072
#define WS_SKTB_OFF (131072 + (1u << 21))
#define WS_NEED_FULL ((size_t)WS_SKTB_OFF + ((size_t)1 << 25))

__device__ __forceinline__ u16 f2bf(float f) {
  unsigned u = __builtin_bit_cast(unsigned, f);
  u += 0x7fffu + ((u >> 16) & 1u);
  return (u16)(u >> 16);
}

__device__ __forceinline__ void gload_lds16(const void* g, void* l) {
  __builtin_amdgcn_global_load_lds(
      (const __attribute__((address_space(1))) unsigned int*)g,
      (__attribute__((address_space(3))) unsigned int*)l, 16, 0, 0);
}

// ---- merged prep: blocks [0,128) do W (colsum, |w-I| partials, bf16 transpose);
//      blocks [128, 128+2048) do A (f32 -> bf16, tiled [kslot][m][8]) ----
template <bool DO_A>
__global__ __launch_bounds__(256) void prep_all(const float* __restrict__ w,
                                                const float* __restrict__ skt,
                                                float* __restrict__ colsum,
                                                float* __restrict__ pabs,
                                                float* __restrict__ psq,
                                                u16* __restrict__ wb,
                                                u16* __restrict__ sktb) {
  __shared__ char smem_u[17440];
  const int t = threadIdx.x;
  const int bid = blockIdx.x;

  if (bid < 128) {
    // ---- W path: block b owns k-rows [b*8, b*8+8) == kslot b ----
    u16(*tile)[1024] = (u16(*)[1024])smem_u;        // 16KB
    float* red = (float*)(smem_u + 16384);          // 8 floats
    const int b = bid;
    const int k0 = b * 8;
    const int col = t * 4;  // this thread owns columns col..col+3 across all 8 rows

    float cs0 = 0.f, cs1 = 0.f, cs2 = 0.f, cs3 = 0.f;
    float aacc = 0.f, sacc = 0.f;
#pragma unroll
    for (int i = 0; i < 8; ++i) {
      const int gk = k0 + i;
      const float4 v = *(const float4*)(w + (size_t)gk * FDIM + col);
      ushort4 bb;
      bb.x = f2bf(v.x); bb.y = f2bf(v.y); bb.z = f2bf(v.z); bb.w = f2bf(v.w);
      *(ushort4*)(&tile[i][col]) = bb;
      cs0 += v.x; cs1 += v.y; cs2 += v.z; cs3 += v.w;
      const float d0 = v.x - (gk == col + 0 ? 1.f : 0.f);
      const float d1 = v.y - (gk == col + 1 ? 1.f : 0.f);
      const float d2 = v.z - (gk == col + 2 ? 1.f : 0.f);
      const float d3 = v.w - (gk == col + 3 ? 1.f : 0.f);
      aacc += fabsf(d0) + fabsf(d1) + fabsf(d2) + fabsf(d3);
      sacc += d0 * d0 + d1 * d1 + d2 * d2 + d3 * d3;
    }
    atomicAdd(&colsum[col + 0], cs0);
    atomicAdd(&colsum[col + 1], cs1);
    atomicAdd(&colsum[col + 2], cs2);
    atomicAdd(&colsum[col + 3], cs3);
#pragma unroll
    for (int off = 1; off < 64; off <<= 1) {
      aacc += __shfl_xor(aacc, off);
      sacc += __shfl_xor(sacc, off);
    }
    const int wid = t >> 6;
    if ((t & 63) == 0) { red[wid] = aacc; red[4 + wid] = sacc; }
    __syncthreads();
    if (t == 0) pabs[b] = red[0] + red[1] + red[2] + red[3];
    if (t == 1) psq[b] = red[4] + red[5] + red[6] + red[7];
    // transpose write (reads only this thread's own columns; no extra sync needed)
#pragma unroll
    for (int j = 0; j < 4; ++j) {
      const int n = col + j;
      u16x8 pk;
#pragma unroll
      for (int e = 0; e < 8; ++e) pk[e] = tile[e][n];
      *(u16x8*)(wb + ((size_t)b * FDIM + n) * 8) = pk;
    }
  } else if constexpr (DO_A) {
    // ---- A path ----
    u16(*tile)[136] = (u16(*)[136])smem_u;  // 64 x 136 u16 = 17408B
    const int ab = bid - 128;
    const int mb = ab >> 3;
    const int kb = ab & 7;
    const int m0 = mb * 64, k0 = kb * 128;
#pragma unroll
    for (int i = 0; i < 8; ++i) {
      const int fid = i * 256 + t;
      const int ml = fid >> 5;
      const int c4 = fid & 31;
      const float4 v = *(const float4*)(skt + (size_t)(m0 + ml) * FDIM + k0 + c4 * 4);
      ushort4 b;
      b.x = f2bf(v.x); b.y = f2bf(v.y); b.z = f2bf(v.z); b.w = f2bf(v.w);
      *(ushort4*)(&tile[ml][c4 * 4]) = b;
    }
    __syncthreads();
    const int ks0 = k0 >> 3;
#pragma unroll
    for (int i = 0; i < 4; ++i) {
      const int uid = i * 256 + t;
      const int si = uid >> 6;
      const int ml = uid & 63;
      const u16x8 pk = *(const u16x8*)(&tile[ml][si * 8]);
      *(u16x8*)(sktb + ((size_t)(ks0 + si) * BROWS + m0 + ml) * 8) = pk;
    }
  }
}

// ---- main: T = skt @ w (bf16 MFMA, BK=64), fused distance epilogue ----
template <bool PRE>
__global__ __launch_bounds__(256, 3) void hofel_main(
    const float* __restrict__ skt, const float* __restrict__ imgp,
    const float* __restrict__ imgn, const u16* __restrict__ wb,
    const u16* __restrict__ sktb, const float* __restrict__ colsum,
    float* __restrict__ rowacc) {
  __shared__ u16 ldsT[16384];  // A: bytes [0,16K) = [8 kslot][128 m][16B]; B: [16K,32K)
  __shared__ float lds_cs[128];

  const int t = threadIdx.x;
  const int lane = t & 63;
  const int wid = t >> 6;
  const int l15 = lane & 15;
  const int l4 = lane >> 4;

  const int swz = (blockIdx.x & 7) * 128 + (blockIdx.x >> 3);
  const int mt = swz >> 3, nt = swz & 7;
  const int m0 = mt * 128, n0 = nt * 128;

  if (t < 128) lds_cs[t] = colsum[n0 + t];

  const int wm = (wid >> 1) * 64;
  const int wn = (wid & 1) * 64;

  f4v acc[4][4];
#pragma unroll
  for (int mi = 0; mi < 4; ++mi)
#pragma unroll
    for (int ni = 0; ni < 4; ++ni) {
      f4v z = {0.f, 0.f, 0.f, 0.f};
      acc[mi][ni] = z;
    }

  for (int kt = 0; kt < 16; ++kt) {
    __syncthreads();  // all waves done reading previous tile
    if constexpr (PRE) {
#pragma unroll
      for (int r = 0; r < 8; ++r) {
        const int o = r * 4096 + wid * 1024;  // wave-uniform LDS byte base
        const int ol = o + lane * 16;
        const char* src;
        if (ol < 16384) {  // A region
          const int s = ol >> 11;            // kslot-in-tile 0..7
          const int m = (ol >> 4) & 127;
          src = (const char*)(sktb + ((size_t)(kt * 8 + s) * BROWS + m0 + m) * 8);
        } else {           // B region
          const int o2 = ol - 16384;
          const int s = o2 >> 11;
          const int n = (o2 >> 4) & 127;
          src = (const char*)(wb + ((size_t)(kt * 8 + s) * FDIM + n0 + n) * 8);
        }
        gload_lds16(src, (char*)ldsT + o);
      }
    } else {
      // B via global_load_lds (4 rounds)
#pragma unroll
      for (int r = 0; r < 4; ++r) {
        const int o = r * 4096 + wid * 1024;
        const int ol = o + lane * 16;
        const int s = ol >> 11;
        const int n = (ol >> 4) & 127;
        gload_lds16((const char*)(wb + ((size_t)(kt * 8 + s) * FDIM + n0 + n) * 8),
                    (char*)ldsT + 16384 + o);
      }
      // A: f32 load + convert + ds_write (128 rows x 64 k)
      const int m = t >> 1, h = t & 1;
      const float* ap = skt + (size_t)(m0 + m) * FDIM + kt * 64 + h * 32;
#pragma unroll
      for (int q = 0; q < 4; ++q) {
        const float4 v0 = *(const float4*)(ap + q * 8);
        const float4 v1 = *(const float4*)(ap + q * 8 + 4);
        u16x8 pk;
        pk[0] = f2bf(v0.x); pk[1] = f2bf(v0.y); pk[2] = f2bf(v0.z); pk[3] = f2bf(v0.w);
        pk[4] = f2bf(v1.x); pk[5] = f2bf(v1.y); pk[6] = f2bf(v1.z); pk[7] = f2bf(v1.w);
        *(u16x8*)((char*)ldsT + ((h * 4 + q) * 128 + m) * 16) = pk;
      }
    }
    __syncthreads();  // staging visible

#pragma unroll
    for (int kk = 0; kk < 2; ++kk) {
      bf8v aF[4], bF[4];
#pragma unroll
      for (int mi = 0; mi < 4; ++mi)
        aF[mi] = *(const bf8v*)((char*)ldsT + (((kk * 4 + l4) * 128) + wm + mi * 16 + l15) * 16);
#pragma unroll
      for (int ni = 0; ni < 4; ++ni)
        bF[ni] = *(const bf8v*)((char*)ldsT + 16384 + (((kk * 4 + l4) * 128) + wn + ni * 16 + l15) * 16);
#pragma unroll
      for (int mi = 0; mi < 4; ++mi)
#pragma unroll
        for (int ni = 0; ni < 4; ++ni)
          acc[mi][ni] = __builtin_amdgcn_mfma_f32_16x16x32_bf16(aF[mi], bF[ni], acc[mi][ni], 0, 0, 0);
    }
  }

  // fused epilogue: rowacc[row] += sum_c (p-n)*(-2*T + (p+n)*colsum[c])
#pragma unroll
  for (int mi = 0; mi < 4; ++mi) {
#pragma unroll
    for (int rr = 0; rr < 4; ++rr) {
      const int row = m0 + wm + mi * 16 + l4 * 4 + rr;
      const float* pr = imgp + (size_t)row * FDIM + n0;
      const float* nr = imgn + (size_t)row * FDIM + n0;
      float s = 0.f;
#pragma unroll
      for (int ni = 0; ni < 4; ++ni) {
        const int cl = wn + ni * 16 + l15;
        const float T = acc[mi][ni][rr];
        const float p = pr[cl];
        const float q = nr[cl];
        s += (p - q) * (-2.f * T + (p + q) * lds_cs[cl]);
      }
#pragma unroll
      for (int off = 1; off < 16; off <<= 1) s += __shfl_xor(s, off);
      if (l15 == 0) atomicAdd(rowacc + row, s);
    }
  }
}

__global__ __launch_bounds__(1024) void hinge_reduce(const float* __restrict__ rowacc,
                                                     float* __restrict__ wsf) {
  __shared__ float part[16];
  const int t = threadIdx.x;
  const int id = blockIdx.x * 1024 + t;
  float v = fmaxf(DELTA_C + rowacc[id], 0.f);
#pragma unroll
  for (int off = 1; off < 64; off <<= 1) v += __shfl_xor(v, off);
  if ((t & 63) == 0) part[t >> 6] = v;
  __syncthreads();
  if (t < 16) {
    float x = part[t];
#pragma unroll
    for (int off = 1; off < 16; off <<= 1) x += __shfl_xor(x, off);
    if (t == 0) atomicAdd(&wsf[0], x);
  }
}

__global__ __launch_bounds__(128) void finalize_k(const float* __restrict__ wsf,
                                                  const float* __restrict__ pabs,
                                                  const float* __restrict__ psq,
                                                  float* __restrict__ out) {
  __shared__ float ra[2], rs[2];
  const int t = threadIdx.x;
  float a = pabs[t], s = psq[t];
#pragma unroll
  for (int off = 1; off < 64; off <<= 1) {
    a += __shfl_xor(a, off);
    s += __shfl_xor(s, off);
  }
  if ((t & 63) == 0) { ra[t >> 6] = a; rs[t >> 6] = s; }
  __syncthreads();
  if (t == 0)
    out[0] = wsf[0] * (1.f / (float)BROWS) +
             LAMB_C * ((ra[0] + ra[1]) + sqrtf(rs[0] + rs[1]));
}

extern "C" void kernel_launch(void* const* d_in, const int* in_sizes, int n_in,
                              void* d_out, int out_size, void* d_ws, size_t ws_size,
                              hipStream_t stream) {
  const float* skt  = (const float*)d_in[0];
  const float* imgp = (const float*)d_in[1];
  const float* imgn = (const float*)d_in[2];
  const float* w    = (const float*)d_in[3];

  float* wsf = (float*)d_ws;
  float* colsum = wsf + 16;
  float* pabs = (float*)((char*)d_ws + WS_PABS_OFF);
  float* psq = (float*)((char*)d_ws + WS_PSQ_OFF);
  float* rowacc = (float*)((char*)d_ws + WS_ROWACC_OFF);
  u16* wb = (u16*)((char*)d_ws + WS_WB_OFF);
  u16* sktb = (u16*)((char*)d_ws + WS_SKTB_OFF);
  float* out = (float*)d_out;

  // zero wsf + colsum + rowacc every call (harness doesn't re-poison)
  hipMemsetAsync(d_ws, 0, WS_ROWACC_OFF + BROWS * sizeof(float), stream);

  if (ws_size >= WS_NEED_FULL) {
    prep_all<true><<<128 + 2048, 256, 0, stream>>>(w, skt, colsum, pabs, psq, wb, sktb);
    hofel_main<true><<<1024, 256, 0, stream>>>(skt, imgp, imgn, wb, sktb, colsum, rowacc);
  } else {
    prep_all<false><<<128, 256, 0, stream>>>(w, skt, colsum, pabs, psq, wb, sktb);
    hofel_main<false><<<1024, 256, 0, stream>>>(skt, imgp, imgn, wb, sktb, colsum, rowacc);
  }

  hinge_reduce<<<16, 1024, 0, stream>>>(rowacc, wsf);
  finalize_k<<<1, 128, 0, stream>>>(wsf, pabs, psq, out);
}

// Round 5
// 87.641 us; speedup vs baseline: 2.4342x; 1.0112x over previous
//
#include <hip/hip_runtime.h>
#include <hip/hip_bf16.h>

#define FDIM 1024
#define BROWS 16384
#define DELTA_C 0.3f
#define LAMB_C 0.0005f

typedef __bf16 bf8v __attribute__((ext_vector_type(8)));
typedef float f4v __attribute__((ext_vector_type(4)));
typedef unsigned short u16;
typedef u16 u16x8 __attribute__((ext_vector_type(8)));

// ws layout (bytes):
//   0    : f32 wsf[16]     (0=hinge)
//   64   : f32 colsum[1024]  (wsf+16)
//   4160 : f32 pabs[128]
//   4672 : f32 psq[128]
//   8192 : f32 rowacc[16384]  (64KB)
//   131072 : wb  bf16 tiled [128 kslot][1024 n][8]   (2MB)  wb[(ks*1024+n)*8+e] = w[ks*8+e][n]
//   131072+2MB : sktb bf16 tiled [128 kslot][16384 m][8] (32MB) sktb[(ks*16384+m)*8+e] = skt[m][ks*8+e]
#define WS_PABS_OFF 4160
#define WS_PSQ_OFF 4672
#define WS_ROWACC_OFF 8192
#define WS_WB_OFF 131072
#define WS_SKTB_OFF (131072 + (1u << 21))
#define WS_NEED_FULL ((size_t)WS_SKTB_OFF + ((size_t)1 << 25))

__device__ __forceinline__ u16 f2bf(float f) {
  unsigned u = __builtin_bit_cast(unsigned, f);
  u += 0x7fffu + ((u >> 16) & 1u);
  return (u16)(u >> 16);
}

__device__ __forceinline__ void gload_lds16(const void* g, void* l) {
  __builtin_amdgcn_global_load_lds(
      (const __attribute__((address_space(1))) unsigned int*)g,
      (__attribute__((address_space(3))) unsigned int*)l, 16, 0, 0);
}

// ---- merged prep: blocks [0,128) do W; blocks [128, 128+2048) do A ----
template <bool DO_A>
__global__ __launch_bounds__(256) void prep_all(const float* __restrict__ w,
                                                const float* __restrict__ skt,
                                                float* __restrict__ colsum,
                                                float* __restrict__ pabs,
                                                float* __restrict__ psq,
                                                u16* __restrict__ wb,
                                                u16* __restrict__ sktb) {
  __shared__ char smem_u[17440];
  const int t = threadIdx.x;
  const int bid = blockIdx.x;

  if (bid < 128) {
    u16(*tile)[1024] = (u16(*)[1024])smem_u;  // 16KB
    float* red = (float*)(smem_u + 16384);
    const int b = bid;
    const int k0 = b * 8;
    const int col = t * 4;

    float cs0 = 0.f, cs1 = 0.f, cs2 = 0.f, cs3 = 0.f;
    float aacc = 0.f, sacc = 0.f;
#pragma unroll
    for (int i = 0; i < 8; ++i) {
      const int gk = k0 + i;
      const float4 v = *(const float4*)(w + (size_t)gk * FDIM + col);
      ushort4 bb;
      bb.x = f2bf(v.x); bb.y = f2bf(v.y); bb.z = f2bf(v.z); bb.w = f2bf(v.w);
      *(ushort4*)(&tile[i][col]) = bb;
      cs0 += v.x; cs1 += v.y; cs2 += v.z; cs3 += v.w;
      const float d0 = v.x - (gk == col + 0 ? 1.f : 0.f);
      const float d1 = v.y - (gk == col + 1 ? 1.f : 0.f);
      const float d2 = v.z - (gk == col + 2 ? 1.f : 0.f);
      const float d3 = v.w - (gk == col + 3 ? 1.f : 0.f);
      aacc += fabsf(d0) + fabsf(d1) + fabsf(d2) + fabsf(d3);
      sacc += d0 * d0 + d1 * d1 + d2 * d2 + d3 * d3;
    }
    atomicAdd(&colsum[col + 0], cs0);
    atomicAdd(&colsum[col + 1], cs1);
    atomicAdd(&colsum[col + 2], cs2);
    atomicAdd(&colsum[col + 3], cs3);
#pragma unroll
    for (int off = 1; off < 64; off <<= 1) {
      aacc += __shfl_xor(aacc, off);
      sacc += __shfl_xor(sacc, off);
    }
    const int wid = t >> 6;
    if ((t & 63) == 0) { red[wid] = aacc; red[4 + wid] = sacc; }
    __syncthreads();
    if (t == 0) pabs[b] = red[0] + red[1] + red[2] + red[3];
    if (t == 1) psq[b] = red[4] + red[5] + red[6] + red[7];
#pragma unroll
    for (int j = 0; j < 4; ++j) {
      const int n = col + j;
      u16x8 pk;
#pragma unroll
      for (int e = 0; e < 8; ++e) pk[e] = tile[e][n];
      *(u16x8*)(wb + ((size_t)b * FDIM + n) * 8) = pk;
    }
  } else if constexpr (DO_A) {
    u16(*tile)[136] = (u16(*)[136])smem_u;  // 64 x 136 u16
    const int ab = bid - 128;
    const int mb = ab >> 3;
    const int kb = ab & 7;
    const int m0 = mb * 64, k0 = kb * 128;
#pragma unroll
    for (int i = 0; i < 8; ++i) {
      const int fid = i * 256 + t;
      const int ml = fid >> 5;
      const int c4 = fid & 31;
      const float4 v = *(const float4*)(skt + (size_t)(m0 + ml) * FDIM + k0 + c4 * 4);
      ushort4 b;
      b.x = f2bf(v.x); b.y = f2bf(v.y); b.z = f2bf(v.z); b.w = f2bf(v.w);
      *(ushort4*)(&tile[ml][c4 * 4]) = b;
    }
    __syncthreads();
    const int ks0 = k0 >> 3;
#pragma unroll
    for (int i = 0; i < 4; ++i) {
      const int uid = i * 256 + t;
      const int si = uid >> 6;
      const int ml = uid & 63;
      const u16x8 pk = *(const u16x8*)(&tile[ml][si * 8]);
      *(u16x8*)(sktb + ((size_t)(ks0 + si) * BROWS + m0 + ml) * 8) = pk;
    }
  }
}

// ---- main: T = skt @ w, BM=256 BN=128 BK=32, 2-phase double-buffered LDS ----
// 512 threads = 8 waves (4M x 2N), per-wave 64x64 output.
// LDS buffer (24KB): A bytes [0,16K) = [4 kslot][256 m][16B]; B [16K,24K) = [4][128][16B]
template <bool PRE>
__global__ __launch_bounds__(512, 4) void hofel_main(
    const float* __restrict__ skt, const float* __restrict__ imgp,
    const float* __restrict__ imgn, const u16* __restrict__ wb,
    const u16* __restrict__ sktb, const float* __restrict__ colsum,
    float* __restrict__ rowacc) {
  __shared__ u16 ldsT[2][12288];  // 2 x 24KB
  __shared__ float lds_cs[128];

  const int t = threadIdx.x;
  const int lane = t & 63;
  const int wid = t >> 6;  // 0..7
  const int l15 = lane & 15;
  const int l4 = lane >> 4;

  // XCD swizzle: 512 blocks, XCD x -> mt in [x*8, x*8+8) (4MB sktb slice = L2)
  const int swz = (blockIdx.x & 7) * 64 + (blockIdx.x >> 3);
  const int mt = swz >> 3, nt = swz & 7;
  const int m0 = mt * 256, n0 = nt * 128;

  const int wr = wid >> 1, wc = wid & 1;
  const int wm = wr * 64, wn = wc * 64;

  f4v acc[4][4];
#pragma unroll
  for (int mi = 0; mi < 4; ++mi)
#pragma unroll
    for (int ni = 0; ni < 4; ++ni) {
      f4v z = {0.f, 0.f, 0.f, 0.f};
      acc[mi][ni] = z;
    }

  // ---- staging helpers (buf = 0/1, kt = k-tile index 0..31) ----
  auto stage = [&](int buf, int kt) {
    if constexpr (PRE) {
#pragma unroll
      for (int r = 0; r < 3; ++r) {
        const int o = r * 8192 + wid * 1024;  // wave-uniform LDS byte offset
        const int ol = o + lane * 16;
        const char* src;
        if (ol < 16384) {  // A region: [4][256][16B]
          const int s = ol >> 12;
          const int m = (ol >> 4) & 255;
          src = (const char*)(sktb + ((size_t)(kt * 4 + s) * BROWS + m0 + m) * 8);
        } else {  // B region: [4][128][16B]
          const int o2 = ol - 16384;
          const int s = o2 >> 11;
          const int n = (o2 >> 4) & 127;
          src = (const char*)(wb + ((size_t)(kt * 4 + s) * FDIM + n0 + n) * 8);
        }
        gload_lds16(src, (char*)ldsT[buf] + o);
      }
    } else {
      // B via global_load_lds (1 round covers 8KB)
      {
        const int o = wid * 1024;
        const int ol = o + lane * 16;
        const int s = ol >> 11;
        const int n = (ol >> 4) & 127;
        gload_lds16((const char*)(wb + ((size_t)(kt * 4 + s) * FDIM + n0 + n) * 8),
                    (char*)ldsT[buf] + 16384 + o);
      }
      // A: f32 -> bf16 conversion, thread owns row m, k-half h (16 floats)
      const int m = t >> 1, h = t & 1;
      const float* ap = skt + (size_t)(m0 + m) * FDIM + kt * 32 + h * 16;
#pragma unroll
      for (int q = 0; q < 2; ++q) {
        const float4 v0 = *(const float4*)(ap + q * 8);
        const float4 v1 = *(const float4*)(ap + q * 8 + 4);
        u16x8 pk;
        pk[0] = f2bf(v0.x); pk[1] = f2bf(v0.y); pk[2] = f2bf(v0.z); pk[3] = f2bf(v0.w);
        pk[4] = f2bf(v1.x); pk[5] = f2bf(v1.y); pk[6] = f2bf(v1.z); pk[7] = f2bf(v1.w);
        *(u16x8*)((char*)ldsT[buf] + (h * 2 + q) * 4096 + m * 16) = pk;
      }
    }
  };

  // prologue: stage tile 0, load colsum
  stage(0, 0);
  if (t < 128) lds_cs[t] = colsum[n0 + t];
  __syncthreads();  // drains vmcnt/lgkm -> tile 0 ready

  int cur = 0;
  for (int kt = 0; kt < 32; ++kt) {
    if (kt < 31) stage(cur ^ 1, kt + 1);  // issue next-tile loads first (hidden under MFMA)

    const char* bufb = (const char*)ldsT[cur];
    bf8v aF[4], bF[4];
#pragma unroll
    for (int mi = 0; mi < 4; ++mi)
      aF[mi] = *(const bf8v*)(bufb + l4 * 4096 + (wm + mi * 16 + l15) * 16);
#pragma unroll
    for (int ni = 0; ni < 4; ++ni)
      bF[ni] = *(const bf8v*)(bufb + 16384 + l4 * 2048 + (wn + ni * 16 + l15) * 16);
#pragma unroll
    for (int mi = 0; mi < 4; ++mi)
#pragma unroll
      for (int ni = 0; ni < 4; ++ni)
        acc[mi][ni] = __builtin_amdgcn_mfma_f32_16x16x32_bf16(aF[mi], bF[ni], acc[mi][ni], 0, 0, 0);

    __syncthreads();  // drains staging (vmcnt+lgkm) AND joins readers before overwrite
    cur ^= 1;
  }

  // fused epilogue: rowacc[row] += sum_c (p-n)*(-2*T + (p+n)*colsum[c])
#pragma unroll
  for (int mi = 0; mi < 4; ++mi) {
#pragma unroll
    for (int rr = 0; rr < 4; ++rr) {
      const int row = m0 + wm + mi * 16 + l4 * 4 + rr;
      const float* pr = imgp + (size_t)row * FDIM + n0;
      const float* nr = imgn + (size_t)row * FDIM + n0;
      float s = 0.f;
#pragma unroll
      for (int ni = 0; ni < 4; ++ni) {
        const int cl = wn + ni * 16 + l15;
        const float T = acc[mi][ni][rr];
        const float p = pr[cl];
        const float q = nr[cl];
        s += (p - q) * (-2.f * T + (p + q) * lds_cs[cl]);
      }
#pragma unroll
      for (int off = 1; off < 16; off <<= 1) s += __shfl_xor(s, off);
      if (l15 == 0) atomicAdd(rowacc + row, s);
    }
  }
}

__global__ __launch_bounds__(1024) void hinge_reduce(const float* __restrict__ rowacc,
                                                     float* __restrict__ wsf) {
  __shared__ float part[16];
  const int t = threadIdx.x;
  const int id = blockIdx.x * 1024 + t;
  float v = fmaxf(DELTA_C + rowacc[id], 0.f);
#pragma unroll
  for (int off = 1; off < 64; off <<= 1) v += __shfl_xor(v, off);
  if ((t & 63) == 0) part[t >> 6] = v;
  __syncthreads();
  if (t < 16) {
    float x = part[t];
#pragma unroll
    for (int off = 1; off < 16; off <<= 1) x += __shfl_xor(x, off);
    if (t == 0) atomicAdd(&wsf[0], x);
  }
}

__global__ __launch_bounds__(128) void finalize_k(const float* __restrict__ wsf,
                                                  const float* __restrict__ pabs,
                                                  const float* __restrict__ psq,
                                                  float* __restrict__ out) {
  __shared__ float ra[2], rs[2];
  const int t = threadIdx.x;
  float a = pabs[t], s = psq[t];
#pragma unroll
  for (int off = 1; off < 64; off <<= 1) {
    a += __shfl_xor(a, off);
    s += __shfl_xor(s, off);
  }
  if ((t & 63) == 0) { ra[t >> 6] = a; rs[t >> 6] = s; }
  __syncthreads();
  if (t == 0)
    out[0] = wsf[0] * (1.f / (float)BROWS) +
             LAMB_C * ((ra[0] + ra[1]) + sqrtf(rs[0] + rs[1]));
}

extern "C" void kernel_launch(void* const* d_in, const int* in_sizes, int n_in,
                              void* d_out, int out_size, void* d_ws, size_t ws_size,
                              hipStream_t stream) {
  const float* skt  = (const float*)d_in[0];
  const float* imgp = (const float*)d_in[1];
  const float* imgn = (const float*)d_in[2];
  const float* w    = (const float*)d_in[3];

  float* wsf = (float*)d_ws;
  float* colsum = wsf + 16;
  float* pabs = (float*)((char*)d_ws + WS_PABS_OFF);
  float* psq = (float*)((char*)d_ws + WS_PSQ_OFF);
  float* rowacc = (float*)((char*)d_ws + WS_ROWACC_OFF);
  u16* wb = (u16*)((char*)d_ws + WS_WB_OFF);
  u16* sktb = (u16*)((char*)d_ws + WS_SKTB_OFF);
  float* out = (float*)d_out;

  // zero wsf + colsum + rowacc every call (harness doesn't re-poison)
  hipMemsetAsync(d_ws, 0, WS_ROWACC_OFF + BROWS * sizeof(float), stream);

  if (ws_size >= WS_NEED_FULL) {
    prep_all<true><<<128 + 2048, 256, 0, stream>>>(w, skt, colsum, pabs, psq, wb, sktb);
    hofel_main<true><<<512, 512, 0, stream>>>(skt, imgp, imgn, wb, sktb, colsum, rowacc);
  } else {
    prep_all<false><<<128, 256, 0, stream>>>(w, skt, colsum, pabs, psq, wb, sktb);
    hofel_main<false><<<512, 512, 0, stream>>>(skt, imgp, imgn, wb, sktb, colsum, rowacc);
  }

  hinge_reduce<<<16, 1024, 0, stream>>>(rowacc, wsf);
  finalize_k<<<1, 128, 0, stream>>>(wsf, pabs, psq, out);
}